// Round 4
// baseline (317.567 us; speedup 1.0000x reference)
//
#include <hip/hip_runtime.h>

#define D 1024
#define NB1 48
#define NB2 48
#define RR 36
#define LL 30
#define NH 4

typedef short bf16x8 __attribute__((ext_vector_type(8)));
typedef float f32x4 __attribute__((ext_vector_type(4)));
typedef float f32x2 __attribute__((ext_vector_type(2)));
typedef unsigned short u16x8 __attribute__((ext_vector_type(8)));

#define MFMA16(a, b, c) __builtin_amdgcn_mfma_f32_16x16x32_bf16(a, b, c, 0, 0, 0)

__device__ __forceinline__ unsigned short f2bf(float x) {
  unsigned u = __float_as_uint(x);
  u += 0x7FFF + ((u >> 16) & 1);
  return (unsigned short)(u >> 16);
}
__device__ __forceinline__ float bf2f(unsigned short h) {
  return __uint_as_float(((unsigned)h) << 16);
}
__device__ __forceinline__ void split8(const float* v, bf16x8& h8, bf16x8& l8) {
  u16x8 hi, lo;
#pragma unroll
  for (int i = 0; i < 8; ++i) {
    unsigned short h = f2bf(v[i]);
    hi[i] = h;
    lo[i] = f2bf(v[i] - bf2f(h));
  }
  h8 = __builtin_bit_cast(bf16x8, hi);
  l8 = __builtin_bit_cast(bf16x8, lo);
}
__device__ __forceinline__ f32x2 shflx2(f32x2 v, int m) {
  double d = __builtin_bit_cast(double, v);
  d = __shfl_xor(d, m);
  return __builtin_bit_cast(f32x2, d);
}

// ---- fp32 row-major (rows x 1024) -> split-bf16 MFMA fragment layout ----
__device__ __forceinline__ void conv_body(const float* __restrict__ X,
                                          unsigned short* __restrict__ out,
                                          int rows, int g) {
  const int lane = threadIdx.x & 63;
  const int tile = g >> 5, kc = g & 31;
  const int row = tile * 16 + (lane & 15);
  const int k = kc * 32 + (lane >> 4) * 8;
  float v[8];
  if (row < rows) {
    const float4* s = (const float4*)(X + (size_t)row * 1024 + k);
    float4 x0 = s[0], x1 = s[1];
    v[0] = x0.x; v[1] = x0.y; v[2] = x0.z; v[3] = x0.w;
    v[4] = x1.x; v[5] = x1.y; v[6] = x1.z; v[7] = x1.w;
  } else {
#pragma unroll
    for (int i = 0; i < 8; ++i) v[i] = 0.f;
  }
  bf16x8 hi, lo;
  split8(v, hi, lo);
  bf16x8* o = (bf16x8*)(out + (size_t)g * 1024 + lane * 8);
  o[0] = hi;
  o[64] = lo;
}

// 6 input matrices in one launch. grid (864, 6)
__global__ __launch_bounds__(256) void conv6(
    const float* __restrict__ v1, const float* __restrict__ v2,
    const float* __restrict__ wimg, const float* __restrict__ wtxt,
    const float* __restrict__ w1a, const float* __restrict__ w1b,
    unsigned short* v1f, unsigned short* v2f, unsigned short* wimgf,
    unsigned short* wtxtf, unsigned short* w1af, unsigned short* w1bf) {
  const float* X; unsigned short* O; int rows;
  switch (blockIdx.y) {
    case 0: X = v1; O = v1f; rows = 1728; break;
    case 1: X = v2; O = v2f; rows = 1440; break;
    case 2: X = wimg; O = wimgf; rows = 1024; break;
    case 3: X = wtxt; O = wtxtf; rows = 1024; break;
    case 4: X = w1a; O = w1af; rows = 1024; break;
    default: X = w1b; O = w1bf; rows = 1024; break;
  }
  const int tiles = (rows + 15) >> 4;
  const int g = blockIdx.x * 4 + (threadIdx.x >> 6);
  if (g >= tiles * 32) return;
  conv_body(X, O, rows, g);
}

// merged conv_k + convG (+ w2 transpose). grid (864, 4)
__global__ __launch_bounds__(256) void convKG(
    const float* __restrict__ k1, const float* __restrict__ k2,
    const float* __restrict__ G2a, const float* __restrict__ G1b,
    const float* __restrict__ w2a, const float* __restrict__ w2b,
    unsigned short* k1f, unsigned short* k2f,
    unsigned short* G2aF, unsigned short* G1bF,
    float4* __restrict__ w2at, float4* __restrict__ w2bt) {
  const int t = threadIdx.x, lane = t & 63;
  const int y = blockIdx.y;
  if (y < 2) {
    const float* X = y ? k2 : k1;
    unsigned short* O = y ? k2f : k1f;
    const int rows = y ? 1440 : 1728;
    const int tiles = (rows + 15) >> 4;
    const int g = blockIdx.x * 4 + (t >> 6);
    if (g >= tiles * 32) return;
    conv_body(X, O, rows, g);
    return;
  }
  if (y == 2 && blockIdx.x < 4) {
    int col = blockIdx.x * 256 + t;
    w2at[col] = make_float4(w2a[col], w2a[1024 + col], w2a[2048 + col], w2a[3072 + col]);
    w2bt[col] = make_float4(w2b[col], w2b[1024 + col], w2b[2048 + col], w2b[3072 + col]);
  }
  if (blockIdx.x >= 768) return;
  const int bb = blockIdx.x >> 4;
  const int nt = ((blockIdx.x & 15) << 2) + (t >> 6);
  const int c = lane & 15, q = lane >> 4;
  if (y == 2) {
    float v[8];
#pragma unroll
    for (int j = 0; j < 8; ++j) {
      int l = q * 8 + j;
      v[j] = (l < LL) ? G2a[(size_t)(bb * LL + l) * D + nt * 16 + c] : 0.f;
    }
    bf16x8 hi, lo;
    split8(v, hi, lo);
    bf16x8* o = (bf16x8*)(G2aF + ((size_t)(bb * 64 + nt) * 2) * 512 + lane * 8);
    o[0] = hi;
    o[64] = lo;
  } else {
#pragma unroll
    for (int kc = 0; kc < 2; ++kc) {
      float v[8];
#pragma unroll
      for (int j = 0; j < 8; ++j) {
        int r = kc * 32 + q * 8 + j;
        v[j] = (r < RR) ? G1b[(size_t)(bb * RR + r) * D + nt * 16 + c] : 0.f;
      }
      bf16x8 hi, lo;
      split8(v, hi, lo);
      bf16x8* o = (bf16x8*)(G1bF + (((size_t)(bb * 64 + nt) * 2 + kc) * 2) * 512 + lane * 8);
      o[0] = hi;
      o[64] = lo;
    }
  }
}

// ---- split-bf16 MFMA GEMM core: 2 waves/block, each 4x4 tiles (128x64 out) ----
#define LOAD_FRAGS(AH, AL, BH, BL)                                              \
  {                                                                             \
    _Pragma("unroll") for (int i = 0; i < 4; ++i) {                             \
      AH[i] = Af[ab[i]]; AL[i] = Af[ab[i] + 64]; ab[i] += 128;                  \
    }                                                                           \
    _Pragma("unroll") for (int j = 0; j < 4; ++j) {                             \
      BH[j] = Bf[bb[j]]; BL[j] = Bf[bb[j] + 64]; bb[j] += 128;                  \
    }                                                                           \
  }

#define MFMA_SET(AH, AL, BH, BL)                                                \
  _Pragma("unroll") for (int i = 0; i < 4; ++i)                                 \
      _Pragma("unroll") for (int j = 0; j < 4; ++j) {                           \
    acc[i][j] = MFMA16(AH[i], BH[j], acc[i][j]);                                \
    acc[i][j] = MFMA16(AL[i], BH[j], acc[i][j]);                                \
    acc[i][j] = MFMA16(AH[i], BL[j], acc[i][j]);                                \
  }

__device__ __forceinline__ void gemm2w_body(const bf16x8* __restrict__ Af,
                                            const bf16x8* __restrict__ Bf,
                                            float* __restrict__ C,
                                            int M, int N, float scale,
                                            int Mtiles, int Ntiles) {
  const int lane = threadIdx.x & 63;
  const int w = threadIdx.x >> 6;          // 0..1
  const int mb = blockIdx.y * 8 + w * 4;
  const int nb = blockIdx.x * 4;
  int ab[4], bb[4];
#pragma unroll
  for (int i = 0; i < 4; ++i) {
    int tm = mb + i; if (tm > Mtiles - 1) tm = Mtiles - 1;
    ab[i] = tm * 4096 + lane;
    int tn = nb + i; if (tn > Ntiles - 1) tn = Ntiles - 1;
    bb[i] = tn * 4096 + lane;
  }
  f32x4 acc[4][4];
#pragma unroll
  for (int i = 0; i < 4; ++i)
#pragma unroll
    for (int j = 0; j < 4; ++j) acc[i][j] = (f32x4){0.f, 0.f, 0.f, 0.f};

  bf16x8 ahA[4], alA[4], bhA[4], blA[4];
  bf16x8 ahB[4], alB[4], bhB[4], blB[4];
  LOAD_FRAGS(ahA, alA, bhA, blA);
#pragma unroll 1
  for (int kc = 0; kc < 30; kc += 2) {
    LOAD_FRAGS(ahB, alB, bhB, blB);
    MFMA_SET(ahA, alA, bhA, blA);
    LOAD_FRAGS(ahA, alA, bhA, blA);
    MFMA_SET(ahB, alB, bhB, blB);
  }
  LOAD_FRAGS(ahB, alB, bhB, blB);
  MFMA_SET(ahA, alA, bhA, blA);
  MFMA_SET(ahB, alB, bhB, blB);

  const int c16 = lane & 15, q = lane >> 4;
#pragma unroll
  for (int i = 0; i < 4; ++i) {
#pragma unroll
    for (int reg = 0; reg < 4; ++reg) {
      int r = (mb + i) * 16 + q * 4 + reg;
      if (r < M) {
#pragma unroll
        for (int j = 0; j < 4; ++j) {
          int col = (nb + j) * 16 + c16;
          if (col < N) C[(size_t)r * N + col] = acc[i][j][reg] * scale;
        }
      }
    }
  }
}

// 4 projection GEMMs. grid (16, 14, 4) x 128
__global__ __launch_bounds__(128) void proj_fused(
    const bf16x8* __restrict__ v1f, const bf16x8* __restrict__ v2f,
    const bf16x8* __restrict__ wimgf, const bf16x8* __restrict__ wtxtf,
    const bf16x8* __restrict__ w1af, const bf16x8* __restrict__ w1bf,
    float* k1, float* k2, float* G2a, float* G1b) {
  const int z = blockIdx.z;
  const bf16x8* Af = (z == 0 || z == 3) ? v1f : v2f;
  const bf16x8* Bf = (z == 0) ? wimgf : (z == 1) ? wtxtf : (z == 2) ? w1af : w1bf;
  float* C = (z == 0) ? k1 : (z == 1) ? k2 : (z == 2) ? G2a : G1b;
  const int M = (z == 0 || z == 3) ? 1728 : 1440;
  const int Mt = (z == 0 || z == 3) ? 108 : 90;
  if ((int)blockIdx.y * 8 >= Mt) return;
  gemm2w_body(Af, Bf, C, M, 1024, 1.f, Mt, 64);
}

// S = k2 * k1^T (scaled). grid (27, 12) x 128
__global__ __launch_bounds__(128) void cross_s(
    const bf16x8* __restrict__ k2f, const bf16x8* __restrict__ k1f,
    float* Sbuf) {
  gemm2w_body(k2f, k1f, Sbuf, 1440, 1728, 0.03125f, 90, 108);
}

// -------- phase A: per-pair double softmax -> split-bf16 P fragments ---------
// grid 576 x 256 (wave per pair). P2F: [b][tile108][part2][512] (rows a*36+r, k=l)
// P1F: [a][tile90][kc2][part2][512] (rows b*30+l, k=r).  MI: [pair][132].
__global__ __launch_bounds__(256) void softmax_frag(
    const float* __restrict__ Sb, unsigned short* __restrict__ P2F,
    unsigned short* __restrict__ P1F, float* __restrict__ MI) {
  const int t = threadIdx.x, lane = t & 63, w = t >> 6;
  const int pair = blockIdx.x * 4 + w;
  const int a = pair / NB2, b = pair - a * NB2;
  __shared__ __align__(16) float Sw_[4][30][36];
  __shared__ float m2s_[4][36], i2s_[4][36], m1s_[4][30], i1s_[4][30];
  float (*Sw)[36] = Sw_[w];
  float* m2s = m2s_[w]; float* i2s = i2s_[w];
  float* m1s = m1s_[w]; float* i1s = i1s_[w];
  const float* Sab = Sb + (size_t)(b * LL) * 1728 + a * RR;
  for (int i = lane; i < LL * RR; i += 64) {
    int l = i / RR, r = i - l * RR;
    Sw[l][r] = Sab[(size_t)l * 1728 + r];
  }
  __builtin_amdgcn_sched_barrier(0);
  float* MIp = MI + (size_t)pair * 132;
  if (lane < RR) {           // dirA: softmax over l for column r
    const int r = lane;
    float m = -1e30f;
    for (int l = 0; l < LL; ++l) m = fmaxf(m, Sw[l][r]);
    float s = 0.f;
    for (int l = 0; l < LL; ++l) s += __expf(Sw[l][r] - m);
    float inv = 1.f / s;
    m2s[r] = m; i2s[r] = inv;
    MIp[r] = m; MIp[36 + r] = inv;
  }
  if (lane < LL) {           // dirB: softmax over r for row l
    const int l = lane;
    float m = -1e30f;
    for (int r = 0; r < RR; ++r) m = fmaxf(m, Sw[l][r]);
    float s = 0.f;
    for (int r = 0; r < RR; ++r) s += __expf(Sw[l][r] - m);
    float inv = 1.f / s;
    m1s[l] = m; i1s[l] = inv;
    MIp[72 + l] = m; MIp[102 + l] = inv;
  }
  __builtin_amdgcn_sched_barrier(0);
  // dirA fragments: row a*36+r, k = l (32)
  for (int i = lane; i < 144; i += 64) {
    int r = i >> 2, q = i & 3;
    int rowg = a * RR + r, tt = rowg >> 4, c = rowg & 15;
    float v[8];
#pragma unroll
    for (int j = 0; j < 8; ++j) {
      int l = q * 8 + j;
      v[j] = (l < LL) ? __expf(Sw[l][r] - m2s[r]) * i2s[r] : 0.f;
    }
    bf16x8 hi, lo;
    split8(v, hi, lo);
    bf16x8* o = (bf16x8*)(P2F + ((size_t)(b * 108 + tt) * 2) * 512 + (q * 16 + c) * 8);
    o[0] = hi;
    o[64] = lo;
  }
  // dirB fragments: row b*30+l, k = r (64 = kc*32+q*8+j)
  for (int i = lane; i < 240; i += 64) {
    int l = i >> 3, kq = i & 7, kc = kq >> 2, q = kq & 3;
    int rowg = b * LL + l, tt = rowg >> 4, c = rowg & 15;
    float v[8];
#pragma unroll
    for (int j = 0; j < 8; ++j) {
      int r = kc * 32 + q * 8 + j;
      v[j] = (r < RR) ? __expf(Sw[l][r] - m1s[l]) * i1s[l] : 0.f;
    }
    bf16x8 hi, lo;
    split8(v, hi, lo);
    bf16x8* o = (bf16x8*)(P1F + (((size_t)(a * 90 + tt) * 2 + kc) * 2) * 512 + (q * 16 + c) * 8);
    o[0] = hi;
    o[64] = lo;
  }
}

// -------- phase B: batched skinny-K score GEMM with fused relu.w2 reduce -----
// grid (27, 48, 2) x 256. z0: SA[b][1728][4]; z1 (x<23): SB[a][1440][4].
__global__ __launch_bounds__(256) void score_gemm(
    const bf16x8* __restrict__ P2Fv, const bf16x8* __restrict__ P1Fv,
    const bf16x8* __restrict__ G2aFv, const bf16x8* __restrict__ G1bFv,
    const float* __restrict__ b1a, const float4* __restrict__ w2at,
    const float* __restrict__ b1b, const float4* __restrict__ w2bt,
    float* __restrict__ SA, float* __restrict__ SB) {
  const int t = threadIdx.x, lane = t & 63, w = t >> 6;
  const int c16 = lane & 15, q = lane >> 4;
  const int x = blockIdx.x, bat = blockIdx.y;
  __shared__ __align__(16) float red[4][64][4];
  f32x2 sc01[4][4], sc23[4][4];
#pragma unroll
  for (int i = 0; i < 4; ++i)
#pragma unroll
    for (int reg = 0; reg < 4; ++reg) {
      sc01[i][reg] = (f32x2){0.f, 0.f};
      sc23[i][reg] = (f32x2){0.f, 0.f};
    }

  if (blockIdx.z == 0) {
    const bf16x8* Pb = P2Fv + (size_t)bat * (108 * 128);
    const bf16x8* Gb = G2aFv + (size_t)bat * (64 * 128);
    bf16x8 aH[4], aL[4];
#pragma unroll
    for (int i = 0; i < 4; ++i) {
      const bf16x8* pp = Pb + (size_t)(x * 4 + i) * 128 + lane;
      aH[i] = pp[0];
      aL[i] = pp[64];
    }
#pragma unroll 2
    for (int it = 0; it < 16; ++it) {
      const int nt = w * 16 + it;
      const bf16x8* gp = Gb + nt * 128 + lane;
      bf16x8 Bh = gp[0], Bl = gp[64];
      const int col = nt * 16 + c16;
      float4 wv = w2at[col];
      float bias = b1a[col];
      f32x2 w01 = {wv.x, wv.y}, w23 = {wv.z, wv.w};
#pragma unroll
      for (int rt = 0; rt < 4; ++rt) {
        f32x4 acc = {bias, bias, bias, bias};
        acc = MFMA16(aH[rt], Bh, acc);
        acc = MFMA16(aL[rt], Bh, acc);
        acc = MFMA16(aH[rt], Bl, acc);
#pragma unroll
        for (int reg = 0; reg < 4; ++reg) {
          float hv = fmaxf(acc[reg], 0.f);
          f32x2 hv2 = {hv, hv};
          sc01[rt][reg] += hv2 * w01;
          sc23[rt][reg] += hv2 * w23;
        }
      }
    }
  } else {
    if (x >= 23) return;
    const bf16x8* Pa = P1Fv + (size_t)bat * (90 * 256);
    const bf16x8* Ga = G1bFv + (size_t)bat * (64 * 256);
    bf16x8 aH[4][2], aL[4][2];
#pragma unroll
    for (int i = 0; i < 4; ++i) {
      int rtc = x * 4 + i; if (rtc > 89) rtc = 89;
      const bf16x8* pp = Pa + (size_t)rtc * 256 + lane;
#pragma unroll
      for (int kc = 0; kc < 2; ++kc) {
        aH[i][kc] = pp[kc * 128];
        aL[i][kc] = pp[kc * 128 + 64];
      }
    }
#pragma unroll 2
    for (int it = 0; it < 16; ++it) {
      const int nt = w * 16 + it;
      const bf16x8* gp = Ga + nt * 256 + lane;
      bf16x8 B0h = gp[0], B0l = gp[64], B1h = gp[128], B1l = gp[192];
      const int col = nt * 16 + c16;
      float4 wv = w2bt[col];
      float bias = b1b[col];
      f32x2 w01 = {wv.x, wv.y}, w23 = {wv.z, wv.w};
#pragma unroll
      for (int rt = 0; rt < 4; ++rt) {
        f32x4 acc = {bias, bias, bias, bias};
        acc = MFMA16(aH[rt][0], B0h, acc);
        acc = MFMA16(aL[rt][0], B0h, acc);
        acc = MFMA16(aH[rt][0], B0l, acc);
        acc = MFMA16(aH[rt][1], B1h, acc);
        acc = MFMA16(aL[rt][1], B1h, acc);
        acc = MFMA16(aH[rt][1], B1l, acc);
#pragma unroll
        for (int reg = 0; reg < 4; ++reg) {
          float hv = fmaxf(acc[reg], 0.f);
          f32x2 hv2 = {hv, hv};
          sc01[rt][reg] += hv2 * w01;
          sc23[rt][reg] += hv2 * w23;
        }
      }
    }
  }
  // reduce over c16 within wave, then across waves via LDS
#pragma unroll
  for (int rt = 0; rt < 4; ++rt)
#pragma unroll
    for (int reg = 0; reg < 4; ++reg) {
      f32x2 v01 = sc01[rt][reg], v23 = sc23[rt][reg];
#pragma unroll
      for (int m = 1; m <= 8; m <<= 1) {
        v01 += shflx2(v01, m);
        v23 += shflx2(v23, m);
      }
      if (c16 == 0) {
        f32x2* rp = (f32x2*)&red[w][rt * 16 + q * 4 + reg][0];
        rp[0] = v01;
        rp[1] = v23;
      }
    }
  __syncthreads();
  {
    int row = t >> 2, h = t & 3;
    float s = red[0][row][h] + red[1][row][h] + red[2][row][h] + red[3][row][h];
    int rowg = x * 64 + row;
    if (blockIdx.z == 0) {
      SA[((size_t)bat * 1728 + rowg) * 4 + h] = s;
    } else if (rowg < 1440) {
      SB[((size_t)bat * 1440 + rowg) * 4 + h] = s;
    }
  }
}

// -------- phase C: per-pair head-softmax + q + u (wave per pair) -------------
__global__ __launch_bounds__(256) void pair_small(
    const float* __restrict__ Sb, const float* __restrict__ SA,
    const float* __restrict__ SB, const float* __restrict__ MI,
    const float* __restrict__ b2a, const float* __restrict__ b2b,
    float* __restrict__ U1buf, float* __restrict__ U2buf) {
  const int t = threadIdx.x, lane = t & 63, w = t >> 6;
  const int pair = blockIdx.x * 4 + w;
  const int a = pair / NB2, b = pair - a * NB2;
  __shared__ float qaS_[4][36], qbS_[4][30], m2S_[4][36], m1S_[4][30];
  float* qaS = qaS_[w]; float* qbS = qbS_[w];
  float* m2S = m2S_[w]; float* m1S = m1S_[w];
  const float* MIp = MI + (size_t)pair * 132;

  // dirA head-softmax over r (36) -> qa[r]
  float4 sv = {0.f, 0.f, 0.f, 0.f};
  if (lane < RR) {
    sv = *(const float4*)&SA[((size_t)b * 1728 + a * RR + lane) * 4];
    sv.x += b2a[0]; sv.y += b2a[1]; sv.z += b2a[2]; sv.w += b2a[3];
  }
  float qa = 0.f;
#pragma unroll
  for (int h = 0; h < 4; ++h) {
    float xv = (lane < RR) ? ((float*)&sv)[h] : -1e30f;
    float m = xv;
#pragma unroll
    for (int o = 1; o < 64; o <<= 1) m = fmaxf(m, __shfl_xor(m, o));
    float ev = (lane < RR) ? __expf(xv - m) : 0.f;
    float s = ev;
#pragma unroll
    for (int o = 1; o < 64; o <<= 1) s += __shfl_xor(s, o);
    qa += ev / s;
  }
  if (lane < RR) {
    qaS[lane] = 0.25f * qa * MIp[36 + lane];
    m2S[lane] = MIp[lane];
  }
  // dirB head-softmax over l (30) -> qb[l]
  float4 sw = {0.f, 0.f, 0.f, 0.f};
  if (lane < LL) {
    sw = *(const float4*)&SB[((size_t)a * 1440 + b * LL + lane) * 4];
    sw.x += b2b[0]; sw.y += b2b[1]; sw.z += b2b[2]; sw.w += b2b[3];
  }
  float qb = 0.f;
#pragma unroll
  for (int h = 0; h < 4; ++h) {
    float xv = (lane < LL) ? ((float*)&sw)[h] : -1e30f;
    float m = xv;
#pragma unroll
    for (int o = 1; o < 64; o <<= 1) m = fmaxf(m, __shfl_xor(m, o));
    float ev = (lane < LL) ? __expf(xv - m) : 0.f;
    float s = ev;
#pragma unroll
    for (int o = 1; o < 64; o <<= 1) s += __shfl_xor(s, o);
    qb += ev / s;
  }
  if (lane < LL) {
    qbS[lane] = 0.25f * qb * MIp[102 + lane];
    m1S[lane] = MIp[72 + lane];
  }
  __builtin_amdgcn_sched_barrier(0);

  const float* Sab = Sb + (size_t)(b * LL) * 1728 + a * RR;
  // u2[l] = sum_r qa[r]*inv2[r]*exp(S[l][r]-m2[r])
  if (lane < LL) {
    float xx = 0.f;
    for (int r = 0; r < RR; ++r)
      xx += qaS[r] * __expf(Sab[(size_t)lane * 1728 + r] - m2S[r]);
    U2buf[((size_t)b * 48 + a) * 32 + lane] = xx;
  }
  // u1[r] = sum_l qb[l]*inv1[l]*exp(S[l][r]-m1[l])
  if (lane < RR) {
    float xx = 0.f;
    for (int l = 0; l < LL; ++l)
      xx += qbS[l] * __expf(Sab[(size_t)l * 1728 + lane] - m1S[l]);
    U1buf[((size_t)a * 48 + b) * 40 + lane] = xx;
  }
}

// Y_A[b] = U2_b(48x30) * V2_b(30x1024) ; Y_B[a] = U1_a(48x36) * V1_a(36x1024)
// grid (48, 2, 4) x 256.
__global__ __launch_bounds__(256) void y_batch(
    const float* __restrict__ v1, const float* __restrict__ v2,
    const float* __restrict__ U1buf, const float* __restrict__ U2buf,
    float* __restrict__ YA, float* __restrict__ YB) {
  const int bb = blockIdx.x;
  const int col = blockIdx.z * 256 + threadIdx.x;
  __shared__ float us[48 * 40];
  float y[48];
#pragma unroll
  for (int i = 0; i < 48; ++i) y[i] = 0.f;
  if (blockIdx.y == 0) {
    for (int i = threadIdx.x; i < 48 * 32; i += 256) us[i] = U2buf[(size_t)bb * 1536 + i];
    __syncthreads();
    const float* V = v2 + (size_t)bb * LL * 1024 + col;
    for (int l = 0; l < LL; ++l) {
      float v = V[(size_t)l * 1024];
#pragma unroll
      for (int i = 0; i < 48; ++i) y[i] = fmaf(us[i * 32 + l], v, y[i]);
    }
    float* Yo = YA + (size_t)bb * 48 * 1024 + col;
#pragma unroll
    for (int i = 0; i < 48; ++i) Yo[(size_t)i * 1024] = y[i];
  } else {
    for (int i = threadIdx.x; i < 48 * 40; i += 256) us[i] = U1buf[(size_t)bb * 1920 + i];
    __syncthreads();
    const float* V = v1 + (size_t)bb * RR * 1024 + col;
    for (int r = 0; r < RR; ++r) {
      float v = V[(size_t)r * 1024];
#pragma unroll
      for (int i = 0; i < 48; ++i) y[i] = fmaf(us[i * 40 + r], v, y[i]);
    }
    float* Yo = YB + (size_t)bb * 48 * 1024 + col;
#pragma unroll
    for (int i = 0; i < 48; ++i) Yo[(size_t)i * 1024] = y[i];
  }
}

// out = (y_A . y_B) / ((|y_A|+eps)(|y_B|+eps)). grid 2304 x 256
__global__ __launch_bounds__(256) void pair_final(
    const float* __restrict__ YA, const float* __restrict__ YB,
    float* __restrict__ out) {
  const int pair = blockIdx.x;
  const int a = pair / NB2;
  const int b = pair - a * NB2;
  const int t = threadIdx.x;
  const float4* ya = (const float4*)(YA + ((size_t)b * 48 + a) * 1024);
  const float4* yb = (const float4*)(YB + ((size_t)a * 48 + b) * 1024);
  float4 va = ya[t], vb = yb[t];
  float num = va.x * vb.x + va.y * vb.y + va.z * vb.z + va.w * vb.w;
  float n1 = va.x * va.x + va.y * va.y + va.z * va.z + va.w * va.w;
  float n2 = vb.x * vb.x + vb.y * vb.y + vb.z * vb.z + vb.w * vb.w;
#pragma unroll
  for (int off = 32; off; off >>= 1) {
    num += __shfl_down(num, off);
    n1 += __shfl_down(n1, off);
    n2 += __shfl_down(n2, off);
  }
  __shared__ float r3[3][4];
  if ((t & 63) == 0) {
    r3[0][t >> 6] = num; r3[1][t >> 6] = n1; r3[2][t >> 6] = n2;
  }
  __syncthreads();
  if (t == 0) {
    float nu = r3[0][0] + r3[0][1] + r3[0][2] + r3[0][3];
    float s1 = sqrtf(fmaxf(r3[1][0] + r3[1][1] + r3[1][2] + r3[1][3], 0.f));
    float s2 = sqrtf(fmaxf(r3[2][0] + r3[2][1] + r3[2][2] + r3[2][3], 0.f));
    out[pair] = nu / ((s1 + 1e-8f) * (s2 + 1e-8f));
  }
}

extern "C" void kernel_launch(void* const* d_in, const int* in_sizes, int n_in,
                              void* d_out, int out_size, void* d_ws, size_t ws_size,
                              hipStream_t stream) {
  const float* v1    = (const float*)d_in[0];
  const float* v2    = (const float*)d_in[1];
  const float* w_img = (const float*)d_in[2];
  const float* w_txt = (const float*)d_in[3];
  const float* w1a   = (const float*)d_in[4];
  const float* b1a   = (const float*)d_in[5];
  const float* w2a   = (const float*)d_in[6];
  const float* b2a   = (const float*)d_in[7];
  const float* w1b   = (const float*)d_in[8];
  const float* b1b   = (const float*)d_in[9];
  const float* w2b   = (const float*)d_in[10];
  const float* b2b   = (const float*)d_in[11];
  float* out = (float*)d_out;

  // fp32 region
  float* ws   = (float*)d_ws;
  float* k1   = ws;                           // 1728*1024
  float* k2   = k1 + (size_t)1728 * 1024;     // 1440*1024
  float* G2a  = k2 + (size_t)1440 * 1024;     // 1440*1024
  float* G1b  = G2a + (size_t)1440 * 1024;    // 1728*1024
  float* Sbuf = G1b + (size_t)1728 * 1024;    // 1440*1728
  float* Cbuf = Sbuf + (size_t)1440 * 1728;   // 1440*1728
  float* g22  = Cbuf + (size_t)1440 * 1728;   // (dead slots kept for layout)
  float* g11  = g22 + (size_t)48 * 900;

  // split-bf16 fragment region
  unsigned short* fb    = (unsigned short*)(g11 + (size_t)48 * 1296);
  unsigned short* v1f   = fb;
  unsigned short* v2f   = v1f + (size_t)108 * 32768;
  unsigned short* k1f   = v2f + (size_t)92 * 32768;
  unsigned short* k2f   = k1f + (size_t)108 * 32768;
  unsigned short* wimgf = k2f + (size_t)92 * 32768;
  unsigned short* wtxtf = wimgf + (size_t)64 * 32768;
  unsigned short* w1af  = wtxtf + (size_t)64 * 32768;
  unsigned short* w1bf  = w1af + (size_t)64 * 32768;
  unsigned short* G2aF  = w1bf + (size_t)64 * 32768;           // 48*65536 ush
  unsigned short* G1bF  = G2aF + (size_t)48 * 65536;           // 48*131072 ush

  // ---- aliases (all stream-ordered safe) ----
  // w2 transposed -> k1 region (dead after convKG reads k1)
  float4* w2at = (float4*)k1;
  float4* w2bt = w2at + 1024;
  // SA/SB/MI -> k2 region (dead after convKG reads k2)
  float* SA = k2;                               // 48*1728*4 = 331776
  float* SB = SA + (size_t)48 * 1728 * 4;       // 48*1440*4 = 276480
  float* MI = SB + (size_t)48 * 1440 * 4;       // 2304*132  = 304128 (<=1474560 total ok)
  // P2F -> G2a+G1b fp32 regions (dead after convKG): 10.6MB <= 12.97MB
  unsigned short* P2F = (unsigned short*)G2a;
  // P1F -> v1f+v2f frag region (dead after proj_fused): 8.85MB <= 13.1MB
  unsigned short* P1F = v1f;
  // YA -> Cbuf head; U bufs -> Cbuf tail (+g22/g11 spill)
  float* YA = Cbuf;                              // 2304*1024
  float* U2buf = Cbuf + (size_t)2304 * 1024;     // 73728
  float* U1buf = U2buf + (size_t)48 * 48 * 32;   // 92160
  // YB -> k1f+k2f frag region (dead after cross_s): 9.44MB <= 13.1MB
  float* YB = (float*)k1f;

  conv6<<<dim3(864, 6), 256, 0, stream>>>(v1, v2, w_img, w_txt, w1a, w1b,
                                          v1f, v2f, wimgf, wtxtf, w1af, w1bf);

  proj_fused<<<dim3(16, 14, 4), 128, 0, stream>>>(
      (const bf16x8*)v1f, (const bf16x8*)v2f, (const bf16x8*)wimgf,
      (const bf16x8*)wtxtf, (const bf16x8*)w1af, (const bf16x8*)w1bf,
      k1, k2, G2a, G1b);

  convKG<<<dim3(864, 4), 256, 0, stream>>>(k1, k2, G2a, G1b, w2a, w2b,
                                           k1f, k2f, G2aF, G1bF, w2at, w2bt);

  cross_s<<<dim3(27, 12), 128, 0, stream>>>(
      (const bf16x8*)k2f, (const bf16x8*)k1f, Sbuf);

  softmax_frag<<<576, 256, 0, stream>>>(Sbuf, P2F, P1F, MI);

  score_gemm<<<dim3(27, 48, 2), 256, 0, stream>>>(
      (const bf16x8*)P2F, (const bf16x8*)P1F,
      (const bf16x8*)G2aF, (const bf16x8*)G1bF,
      b1a, w2at, b1b, w2bt, SA, SB);

  pair_small<<<576, 256, 0, stream>>>(Sbuf, SA, SB, MI, b2a, b2b, U1buf, U2buf);

  y_batch<<<dim3(48, 2, 4), 256, 0, stream>>>(v1, v2, U1buf, U2buf, YA, YB);
  pair_final<<<2304, 256, 0, stream>>>(YA, YB, out);
}